// Round 2
// baseline (75.364 us; speedup 1.0000x reference)
//
#include <hip/hip_runtime.h>

// out[b,u] = prod_f(inputs[b,f] * weight[f,u]) + bias[u]
//          = (prod_f inputs[b,f]) * (prod_f weight[f,u]) + bias[u]
// B=32768, F=32, U=256.
// R4: kill per-block serialization. Row products now fully in-register via
// __shfl_xor over 8-lane groups (thread tid owns the float4 of row tid>>3);
// each wave stores its OWN 8 rows with a wave-wide __shfl broadcast of pin.
// Deletes partial[], pin_s[], one __syncthreads, and the 32-of-256-thread
// serial reduction. Single remaining barrier guards pw_s only.
// NT load/store kept from R3 (out/in are touch-once; weight stays L2-hot).
// Mandatory traffic: 4MB in + 32MB out -> ~5.8us at 6.3 TB/s achievable.

#define F 32
#define U 256
#define ROWS_PER_BLOCK 32

typedef float f32x4 __attribute__((ext_vector_type(4)));

__global__ __launch_bounds__(256)
void fused_kernel(const float* __restrict__ inp,
                  const float* __restrict__ weight,
                  const float* __restrict__ bias,
                  float* __restrict__ out) {
  __shared__ float pw_s[U];   // per-column weight products (only LDS left)

  const int tid  = threadIdx.x;
  const int lane = tid & 63;
  const int wave = tid >> 6;
  const int base = blockIdx.x * ROWS_PER_BLOCK;

  // ---- input: issue FIRST (cold HBM). Thread tid covers row tid>>3,
  // floats [(tid&7)*4 .. +3]. 8 threads span one 32-float row. ----
  const int row = tid >> 3;  // 0..31
  const f32x4 x = __builtin_nontemporal_load(
      (const f32x4*)(inp + (size_t)(base + row) * F + (tid & 7) * 4));

  // ---- Pw[u]: one column per thread; coalesced; L2-hot across 1024 blocks ----
  {
    float p = 1.0f;
#pragma unroll
    for (int f = 0; f < F; ++f) p *= weight[f * U + tid];
    pw_s[tid] = p;
  }

  // ---- row product in-register: xor-shuffle product over the 8-lane group.
  // After this every lane in group g of wave w holds pin[8w + g]. ----
  float m = x.x * x.y * x.z * x.w;
  m *= __shfl_xor(m, 1);
  m *= __shfl_xor(m, 2);
  m *= __shfl_xor(m, 4);

  __syncthreads();  // pw_s ready

  const f32x4 w4 = *(const f32x4*)(&pw_s[lane * 4]);
  const f32x4 b4 = *(const f32x4*)(bias + lane * 4);

  // ---- epilogue: wave w stores its own rows 8w..8w+7; pin via wave-wide
  // broadcast from lane g*8. 1KB per store step, fully coalesced, NT. ----
#pragma unroll
  for (int g = 0; g < 8; ++g) {
    const float pin = __shfl(m, g * 8);
    const int r = wave * 8 + g;
    f32x4 o;
    o.x = pin * w4.x + b4.x;
    o.y = pin * w4.y + b4.y;
    o.z = pin * w4.z + b4.z;
    o.w = pin * w4.w + b4.w;
    __builtin_nontemporal_store(o, (f32x4*)(out + (size_t)(base + r) * U + lane * 4));
  }
}

extern "C" void kernel_launch(void* const* d_in, const int* in_sizes, int n_in,
                              void* d_out, int out_size, void* d_ws, size_t ws_size,
                              hipStream_t stream) {
  const float* inp    = (const float*)d_in[0];  // [B, F]
  const float* weight = (const float*)d_in[1];  // [F, U]
  // d_in[2] = weight_selector: dead code in the reference, unused
  const float* bias   = (const float*)d_in[3];  // [U]
  float* out = (float*)d_out;                   // [B, U]

  const int B = in_sizes[0] / F;
  fused_kernel<<<B / ROWS_PER_BLOCK, 256, 0, stream>>>(inp, weight, bias, out);
}